// Round 1
// baseline (136.795 us; speedup 1.0000x reference)
//
#include <hip/hip_runtime.h>
#include <math.h>

#define BB 4
#define HH 64
#define WW 64
#define CC 128
#define NPATCH 26   // 25 shifted ref patches + self

// One wave (64 lanes) per pixel; 4 waves / 256-thread block.
__global__ __launch_bounds__(256) void local_attn_kernel(
    const float* __restrict__ main_,
    const float* __restrict__ main_value,
    const float* __restrict__ ref,
    const float* __restrict__ ref_value,
    float* __restrict__ out)
{
    const int wave = threadIdx.x >> 6;
    const int lane = threadIdx.x & 63;
    const int pix  = blockIdx.x * 4 + wave;          // ((b*H + h)*W + w)
    const int w = pix & (WW - 1);
    const int h = (pix / WW) & (HH - 1);
    const int b = pix / (WW * HH);

    const float* mainv = main_ + (size_t)pix * CC;

    // ---------- phase 1: logits (lane n owns patch n) ----------
    float logit = 0.f;
    if (lane < NPATCH) {
        bool valid = true;
        const float* src = mainv;                    // lane 25: self
        if (lane < 25) {
            const int dy = lane / 5 - 2, dx = lane % 5 - 2;
            const int hh = h + dy, ww = w + dx;
            valid = (hh >= 0) && (hh < HH) && (ww >= 0) && (ww < WW);
            const int hc = valid ? hh : 0, wc = valid ? ww : 0;
            src = ref + ((size_t)((b * HH + hc) * WW + wc)) * CC;
        }
        if (valid) {
            float acc = 0.f;
            const float4* m4 = (const float4*)mainv;
            const float4* r4 = (const float4*)src;
            #pragma unroll 4
            for (int c4 = 0; c4 < CC / 4; ++c4) {
                float4 m = m4[c4];
                float4 r = r4[c4];
                acc += m.x * r.x + m.y * r.y + m.z * r.z + m.w * r.w;
            }
            logit = acc;
        }
        // zero-padded OOB neighbor: dot with zeros -> logit stays 0 (must
        // still participate in softmax with a zero value vector)
    }

    // ---------- phase 2: softmax over 26 lanes ----------
    float v = (lane < NPATCH) ? logit : -INFINITY;
    #pragma unroll
    for (int off = 32; off; off >>= 1) v = fmaxf(v, __shfl_xor(v, off));
    const float mx = v;
    float e = (lane < NPATCH) ? __expf(logit - mx) : 0.f;
    float s = e;
    #pragma unroll
    for (int off = 32; off; off >>= 1) s += __shfl_xor(s, off);
    const float attn = e / s;   // valid on lanes 0..25

    // ---------- phase 3: weighted value sum (lanes over channels) ----------
    // lane handles channels 2*lane, 2*lane+1
    const float2* mv2 = (const float2*)(main_value + (size_t)pix * CC);
    const float2  mvv = mv2[lane];
    float ox = 0.f, oy = 0.f;
    #pragma unroll
    for (int n = 0; n < 25; ++n) {
        const float a = __shfl(attn, n);
        const int dy = n / 5 - 2, dx = n % 5 - 2;
        const int hh = h + dy, ww = w + dx;
        if (hh >= 0 && hh < HH && ww >= 0 && ww < WW) {   // wave-uniform branch
            const float2* rv2 =
                (const float2*)(ref_value + ((size_t)((b * HH + hh) * WW + ww)) * CC);
            const float2 rv = rv2[lane];
            ox += a * rv.x;
            oy += a * rv.y;
        }
        // OOB: value vector is zero -> no contribution (weight already in denom)
    }
    const float a25 = __shfl(attn, 25);
    ox += a25 * mvv.x;
    oy += a25 * mvv.y;

    float2* o2 = (float2*)(out + (size_t)pix * CC);
    o2[lane] = make_float2(ox, oy);
}

extern "C" void kernel_launch(void* const* d_in, const int* in_sizes, int n_in,
                              void* d_out, int out_size, void* d_ws, size_t ws_size,
                              hipStream_t stream) {
    const float* main_      = (const float*)d_in[0];
    const float* main_value = (const float*)d_in[1];
    const float* ref        = (const float*)d_in[2];
    const float* ref_value  = (const float*)d_in[3];
    float* out = (float*)d_out;

    const int npix = BB * HH * WW;            // 16384
    dim3 grid(npix / 4), block(256);
    local_attn_kernel<<<grid, block, 0, stream>>>(main_, main_value, ref, ref_value, out);
}

// Round 2
// 101.869 us; speedup vs baseline: 1.3429x; 1.3429x over previous
//
#include <hip/hip_runtime.h>
#include <math.h>

#define HH 64
#define WW 64
#define CC 128
#define TH 4
#define TW 8
#define HALO_H (TH + 4)        // 8
#define HALO_W 13              // 12 real halo cols + 1 spare (bank spread via p = hy*13+hx)
#define NROWS (HALO_H * HALO_W) // 104
#define ROW_F2 65              // float2 per LDS row: 64 + 1 pad -> 130 floats -> +2 banks/row

// Block: 512 threads (8 waves) handles a TH x TW pixel tile of one batch image.
// LDS: ref halo tile, 104 rows x 65 float2 = 54,080 B -> 2 blocks/CU.
__global__ __launch_bounds__(512, 4) void local_attn_lds(
    const float* __restrict__ main_,
    const float* __restrict__ main_value,
    const float* __restrict__ ref,
    const float* __restrict__ ref_value,
    float* __restrict__ out)
{
    __shared__ float2 refS[NROWS * ROW_F2];

    const int tid = threadIdx.x;
    const int bid = blockIdx.x;
    const int b  = bid >> 7;          // 128 tiles per batch
    const int th = (bid >> 3) & 15;   // 16 h-tiles
    const int tw = bid & 7;           // 8 w-tiles
    const int h0 = th * TH, w0 = tw * TW;

    // ---------- stage ref halo tile (coalesced float2) ----------
    const float2* ref2 = (const float2*)ref;
    #pragma unroll
    for (int i = 0; i < 13; ++i) {             // 13 * 512 = 6656 = 104 rows * 64 f2
        int idx = tid + (i << 9);
        int row = idx >> 6, c2 = idx & 63;
        int hy = row / 13, hx = row - hy * 13;
        int gh = h0 - 2 + hy; gh = gh < 0 ? 0 : (gh > HH - 1 ? HH - 1 : gh);
        int gw = w0 - 2 + hx; gw = gw < 0 ? 0 : (gw > WW - 1 ? WW - 1 : gw);
        refS[row * ROW_F2 + c2] = ref2[(((b * HH + gh) * WW) + gw) * 64 + c2];
    }
    __syncthreads();

    const int lane = tid & 63;
    const int wv   = tid >> 6;        // wave id 0..7
    const int half = lane >> 5;       // 0/1: which pixel of the pair
    const int l    = lane & 31;       // role within half

    for (int pp = 0; pp < 2; ++pp) {
        const int t  = ((wv << 1) + pp) * 2 + half;   // tile-pixel 0..31
        const int ty = t >> 3, tx = t & 7;
        const int px = (b * HH + h0 + ty) * WW + (w0 + tx);

        // ---------- phase 1: logits, lane l<26 owns neighbor l (25 = self) ----------
        const bool active = (l < 26);
        const bool self   = (l == 25);
        int dy = 0, dx = 0;
        bool valid = true;
        if (l < 25) {
            dy = l / 5 - 2; dx = l % 5 - 2;
            int gh = h0 + ty + dy, gw = w0 + tx + dx;
            valid = (gh >= 0) & (gh < HH) & (gw >= 0) & (gw < WW);
        }
        const int cdy = valid ? dy : 0, cdx = valid ? dx : 0;   // clamp to center row if OOB
        const float2* m2 = (const float2*)(main_ + (size_t)px * CC);
        const float2* r2 = refS + ((ty + 2 + cdy) * 13 + (tx + 2 + cdx)) * ROW_F2;

        float acc0 = 0.f, acc1 = 0.f;
        #pragma unroll 8
        for (int c = 0; c < 64; c += 2) {
            float2 ma = m2[c],     mb = m2[c + 1];   // half-uniform addr -> broadcast, L1-hot
            float2 ra = r2[c],     rb = r2[c + 1];   // ds_read_b64, <=2-way conflicts
            if (self) { ra = ma; rb = mb; }          // self logit = dot(main, main)
            acc0 += ma.x * ra.x + ma.y * ra.y;
            acc1 += mb.x * rb.x + mb.y * rb.y;
        }
        float logit = (active && valid) ? (acc0 + acc1) : 0.f;  // OOB neighbor: logit 0 (zero-pad)

        // ---------- phase 2: softmax over 26 lanes within each 32-lane half ----------
        float vmax = active ? logit : -INFINITY;
        #pragma unroll
        for (int off = 16; off; off >>= 1) vmax = fmaxf(vmax, __shfl_xor(vmax, off));
        float e = active ? __expf(logit - vmax) : 0.f;
        float s = e;
        #pragma unroll
        for (int off = 16; off; off >>= 1) s += __shfl_xor(s, off);
        const float attn = e / s;

        // ---------- phase 3: weighted value sum, lane l covers channels 4l..4l+3 ----------
        const float4* rv4 = (const float4*)ref_value;
        float4 o = make_float4(0.f, 0.f, 0.f, 0.f);
        #pragma unroll 5
        for (int n = 0; n < 25; ++n) {
            const float a = __shfl(attn, (lane & 32) | n);
            const int ndy = n / 5 - 2, ndx = n % 5 - 2;
            const int gh = h0 + ty + ndy, gw = w0 + tx + ndx;
            if (gh >= 0 && gh < HH && gw >= 0 && gw < WW) {   // uniform within half
                const float4 v = rv4[((b * HH + gh) * WW + gw) * 32 + l];
                o.x += a * v.x; o.y += a * v.y; o.z += a * v.z; o.w += a * v.w;
            }
        }
        const float a25 = __shfl(attn, (lane & 32) | 25);
        const float4 mv = ((const float4*)main_value)[(size_t)px * 32 + l];
        o.x += a25 * mv.x; o.y += a25 * mv.y; o.z += a25 * mv.z; o.w += a25 * mv.w;

        ((float4*)out)[(size_t)px * 32 + l] = o;
    }
}

extern "C" void kernel_launch(void* const* d_in, const int* in_sizes, int n_in,
                              void* d_out, int out_size, void* d_ws, size_t ws_size,
                              hipStream_t stream) {
    const float* main_      = (const float*)d_in[0];
    const float* main_value = (const float*)d_in[1];
    const float* ref        = (const float*)d_in[2];
    const float* ref_value  = (const float*)d_in[3];
    float* out = (float*)d_out;

    dim3 grid(4 * 16 * 8), block(512);   // 512 blocks, 2 per CU
    local_attn_lds<<<grid, block, 0, stream>>>(main_, main_value, ref, ref_value, out);
}

// Round 3
// 101.454 us; speedup vs baseline: 1.3483x; 1.0041x over previous
//
#include <hip/hip_runtime.h>
#include <math.h>

#define HH 64
#define WW 64
#define CC 128
#define ROW_F2 65          // float2 stride per LDS row (130 floats -> rows offset by 2 banks)
#define HALO_ROWS 104      // 8 x 13 (12 real halo cols + 1 spare)
#define MAIN_ROW0 104      // 32 main-pixel rows follow the halo
#define NROWS 136          // 136 * 65 * 8 B = 70,720 B -> 2 blocks/CU

// Block: 512 threads (8 waves) handles a 4x8 pixel tile of one batch image.
// Phase 1 is pure-LDS (ref halo + main rows both staged); phase 3 reads
// ref_value from global (L1/L2) with all attn broadcasts hoisted.
__global__ __launch_bounds__(512, 4) void local_attn_lds2(
    const float* __restrict__ main_,
    const float* __restrict__ main_value,
    const float* __restrict__ ref,
    const float* __restrict__ ref_value,
    float* __restrict__ out)
{
    __shared__ float2 S[NROWS * ROW_F2];

    const int tid = threadIdx.x;
    const int bid = blockIdx.x;
    const int b  = bid >> 7;          // 128 tiles per batch image
    const int th = (bid >> 3) & 15;   // 16 h-tiles
    const int tw = bid & 7;           // 8 w-tiles
    const int h0 = th * 4, w0 = tw * 8;

    // ---------- stage ref halo (104 rows) + main rows (32) ----------
    const float4* ref4 = (const float4*)ref;
    #pragma unroll
    for (int i = 0; i < 7; ++i) {              // 104 rows * 32 f4 = 3328
        int idx = tid + (i << 9);
        if (idx < 3328) {
            int row = idx >> 5, c4 = idx & 31;
            int hy = row / 13, hx = row - hy * 13;
            int gh = h0 - 2 + hy; gh = gh < 0 ? 0 : (gh > 63 ? 63 : gh);
            int gw = w0 - 2 + hx; gw = gw < 0 ? 0 : (gw > 63 ? 63 : gw);
            float4 v = ref4[((((b << 6) + gh) << 6) | gw) * 32 + c4];
            float2* d = S + row * ROW_F2 + (c4 << 1);
            d[0] = make_float2(v.x, v.y);
            d[1] = make_float2(v.z, v.w);
        }
    }
    const float4* main4 = (const float4*)main_;
    #pragma unroll
    for (int i = 0; i < 2; ++i) {              // 32 rows * 32 f4 = 1024
        int idx = tid + (i << 9);
        int t = idx >> 5, c4 = idx & 31;
        int ty = t >> 3, tx = t & 7;
        float4 v = main4[((((b << 6) + (h0 + ty)) << 6) | (w0 + tx)) * 32 + c4];
        float2* d = S + (MAIN_ROW0 + t) * ROW_F2 + (c4 << 1);
        d[0] = make_float2(v.x, v.y);
        d[1] = make_float2(v.z, v.w);
    }
    __syncthreads();

    const int lane = tid & 63;
    const int wv   = tid >> 6;
    const int half = lane >> 5;
    const int l    = lane & 31;

    for (int pp = 0; pp < 2; ++pp) {
        const int t  = ((wv << 1) + pp) * 2 + half;   // tile-pixel 0..31
        const int ty = t >> 3, tx = t & 7;
        const int px = (b * HH + h0 + ty) * WW + (w0 + tx);

        // ---------- phase 1: logits, all operands in LDS ----------
        const bool active = (l < 26);
        int dy = 0, dx = 0;
        bool valid = true;
        if (l < 25) {
            dy = l / 5 - 2; dx = l % 5 - 2;
            int gh = h0 + ty + dy, gw = w0 + tx + dx;
            valid = (gh >= 0) & (gh < HH) & (gw >= 0) & (gw < WW);
        }
        int srow;
        if (l >= 25) srow = MAIN_ROW0 + t;            // self (lane 25) + idle lanes
        else {
            int cdy = valid ? dy : 0, cdx = valid ? dx : 0;
            srow = (ty + 2 + cdy) * 13 + (tx + 2 + cdx);
        }
        const float2* mrow = S + (MAIN_ROW0 + t) * ROW_F2;  // half-uniform -> broadcast
        const float2* rrow = S + srow * ROW_F2;

        float acc0 = 0.f, acc1 = 0.f;
        #pragma unroll 8
        for (int c = 0; c < 64; c += 2) {
            float2 ma = mrow[c],     mb = mrow[c + 1];
            float2 ra = rrow[c],     rb = rrow[c + 1];
            acc0 += ma.x * ra.x + ma.y * ra.y;
            acc1 += mb.x * rb.x + mb.y * rb.y;
        }
        const float logit = (active && valid) ? (acc0 + acc1) : 0.f;

        // ---------- phase 2: softmax over 26 lanes within each half ----------
        float vmax = active ? logit : -INFINITY;
        #pragma unroll
        for (int off = 16; off; off >>= 1) vmax = fmaxf(vmax, __shfl_xor(vmax, off));
        float e = active ? __expf(logit - vmax) : 0.f;
        float s = e;
        #pragma unroll
        for (int off = 16; off; off >>= 1) s += __shfl_xor(s, off);
        const float attn = e / s;

        // ---------- phase 3: weighted value sum, lane l -> channels 4l..4l+3 ----------
        float a[26];
        #pragma unroll
        for (int n = 0; n < 26; ++n) a[n] = __shfl(attn, (lane & 32) | n);

        const float4* rv4 = (const float4*)ref_value;
        float4 o = make_float4(0.f, 0.f, 0.f, 0.f);
        #pragma unroll
        for (int n = 0; n < 25; ++n) {
            const int ndy = n / 5 - 2, ndx = n % 5 - 2;
            const int gh = h0 + ty + ndy, gw = w0 + tx + ndx;
            if (gh >= 0 && gh < HH && gw >= 0 && gw < WW) {
                const float4 v = rv4[(((b << 6) + gh) << 6 | gw) * 32 + l];
                o.x += a[n] * v.x; o.y += a[n] * v.y;
                o.z += a[n] * v.z; o.w += a[n] * v.w;
            }
        }
        const float4 mv = ((const float4*)main_value)[(size_t)px * 32 + l];
        o.x += a[25] * mv.x; o.y += a[25] * mv.y;
        o.z += a[25] * mv.z; o.w += a[25] * mv.w;

        ((float4*)out)[(size_t)px * 32 + l] = o;
    }
}

extern "C" void kernel_launch(void* const* d_in, const int* in_sizes, int n_in,
                              void* d_out, int out_size, void* d_ws, size_t ws_size,
                              hipStream_t stream) {
    const float* main_      = (const float*)d_in[0];
    const float* main_value = (const float*)d_in[1];
    const float* ref        = (const float*)d_in[2];
    const float* ref_value  = (const float*)d_in[3];
    float* out = (float*)d_out;

    dim3 grid(4 * 16 * 8), block(512);   // 512 blocks, 2 per CU
    local_attn_lds2<<<grid, block, 0, stream>>>(main_, main_value, ref, ref_value, out);
}

// Round 4
// 99.064 us; speedup vs baseline: 1.3809x; 1.0241x over previous
//
#include <hip/hip_runtime.h>
#include <math.h>

typedef _Float16 v8h __attribute__((ext_vector_type(8)));
typedef float    v4f __attribute__((ext_vector_type(4)));

// LDS layout (exactly 65536 B):
//  B16 region [0, 32768): 128 rows x 128 fp16 (256 B rows, XOR-swizzled 16B chunks)
//      rows 0..95  = ref halo (8x12, zero rows for OOB -> exact zero-pad semantics)
//      rows 96..127 = main pixel rows (fp16 hi) == A_hi
//      REUSED in epoch 3/4 as VT: rows = value-channel c, cols = position 0..127
//  ALO [32768, 40960): 32 rows x 128 fp16 = lo part of main (fp16x2 split)
//  L   [40960, 57344): 32 x 128 fp32 logits (no pad; ~2-4 way conflicts, few insts)
//  P   [57344, 65536): 32 x 128 fp16 attn matrix (zero except 26 cols/row)
#define B_OFF   0
#define ALO_OFF 32768
#define L_OFF   40960
#define P_OFF   57344

// byte offset of 16B chunk c16 in row r (256 B rows, XOR bank swizzle)
__device__ __forceinline__ int swz(int r, int c16) {
    return (r << 8) + ((c16 ^ (r & 15)) << 4);
}

__global__ __launch_bounds__(512, 4) void local_attn_mfma(
    const float* __restrict__ main_,
    const float* __restrict__ main_value,
    const float* __restrict__ ref,
    const float* __restrict__ ref_value,
    float* __restrict__ out)
{
    __shared__ __align__(16) char S[65536];

    const int tid = threadIdx.x;
    const int bid = blockIdx.x;
    const int b  = bid >> 7;
    const int h0 = ((bid >> 3) & 15) << 2;   // 4-row tiles
    const int w0 = (bid & 7) << 3;           // 8-col tiles

    // ================= epoch 1: stage B16 (+A_lo), zero P =================
    {
        const int r = tid >> 2;          // 0..127: B row
        const int q = tid & 3;           // channel quarter (32 ch)
        const float* src;
        bool valid = true;
        if (r < 96) {
            const int hy = r / 12, hx = r - hy * 12;
            const int gh = h0 - 2 + hy, gw = w0 - 2 + hx;
            valid = (gh >= 0) & (gh < 64) & (gw >= 0) & (gw < 64);
            src = ref + (size_t)((((b << 6) + (valid ? gh : 0)) << 6) + (valid ? gw : 0)) * 128;
        } else {
            const int t = r - 96;
            src = main_ + (size_t)((((b << 6) + h0 + (t >> 3)) << 6) + (w0 + (t & 7))) * 128;
        }
        #pragma unroll
        for (int g = 0; g < 4; ++g) {    // 4 chunks of 8 channels
            const int cbase = (q << 5) + (g << 3);
            float a8[8];
            const float4 v0 = valid ? *(const float4*)(src + cbase)     : make_float4(0,0,0,0);
            const float4 v1 = valid ? *(const float4*)(src + cbase + 4) : make_float4(0,0,0,0);
            a8[0]=v0.x; a8[1]=v0.y; a8[2]=v0.z; a8[3]=v0.w;
            a8[4]=v1.x; a8[5]=v1.y; a8[6]=v1.z; a8[7]=v1.w;
            v8h hi;
            #pragma unroll
            for (int j = 0; j < 8; ++j) hi[j] = (_Float16)a8[j];
            *(v8h*)(S + B_OFF + swz(r, (q << 2) + g)) = hi;
            if (r >= 96) {               // lo part of main (fp16x2 split)
                v8h lo;
                #pragma unroll
                for (int j = 0; j < 8; ++j) lo[j] = (_Float16)(a8[j] - (float)hi[j]);
                *(v8h*)(S + ALO_OFF + swz(r - 96, (q << 2) + g)) = lo;
            }
        }
        *(uint4*)(S + P_OFF + tid * 16) = make_uint4(0, 0, 0, 0);   // zero P
    }
    __syncthreads();

    const int lane = tid & 63, w = tid >> 6;
    const int l15 = lane & 15, quad = lane >> 4;
    const int mt  = w >> 2;              // m-tile (16 pixels)
    const int ntp = (w & 3) << 1;        // first of 2 n-tiles

    // ================= epoch 2: L = (A_hi + A_lo) * B^T via MFMA ==========
    {
        const int arow = 96 + (mt << 4) + l15;   // A_hi lives in B16 rows 96..127
        const int lrow = (mt << 4) + l15;        // A_lo row
        const int b0r  = (ntp << 4) + l15, b1r = b0r + 16;
        v4f acc0 = {0,0,0,0}, acc1 = {0,0,0,0};
        #pragma unroll
        for (int ks = 0; ks < 4; ++ks) {
            const int c16 = (ks << 2) + quad;
            const v8h ahi = *(const v8h*)(S + B_OFF   + swz(arow, c16));
            const v8h alo = *(const v8h*)(S + ALO_OFF + swz(lrow, c16));
            const v8h bb0 = *(const v8h*)(S + B_OFF   + swz(b0r,  c16));
            const v8h bb1 = *(const v8h*)(S + B_OFF   + swz(b1r,  c16));
            acc0 = __builtin_amdgcn_mfma_f32_16x16x32_f16(ahi, bb0, acc0, 0, 0, 0);
            acc0 = __builtin_amdgcn_mfma_f32_16x16x32_f16(alo, bb0, acc0, 0, 0, 0);
            acc1 = __builtin_amdgcn_mfma_f32_16x16x32_f16(ahi, bb1, acc1, 0, 0, 0);
            acc1 = __builtin_amdgcn_mfma_f32_16x16x32_f16(alo, bb1, acc1, 0, 0, 0);
        }
        // C layout: col = lane&15, row = quad*4 + reg  (m89, dtype-independent)
        #pragma unroll
        for (int j = 0; j < 4; ++j) {
            const int px = (mt << 4) + (quad << 2) + j;
            *(float*)(S + L_OFF + (px << 9) + ((((ntp    ) << 4) + l15) << 2)) = acc0[j];
            *(float*)(S + L_OFF + (px << 9) + ((((ntp + 1) << 4) + l15) << 2)) = acc1[j];
        }
    }
    __syncthreads();

    // ========= epoch 3: VT staging (overwrites B16) + softmax -> P =========
    {
        // VT[c][pos]: transpose-stage values, zero rows for OOB positions
        #pragma unroll
        for (int i = 0; i < 4; ++i) {
            const int tk = w + (i << 3);              // 0..31 tasks
            const int pb = tk & 15;                   // position block (8 pos)
            const int ch = ((tk >> 4) << 6) + lane;   // value channel 0..127
            v8h hv;
            #pragma unroll
            for (int j = 0; j < 8; ++j) {
                const int pos = (pb << 3) + j;        // wave-uniform
                float v;
                if (pos < 96) {
                    const int hy = pos / 12, hx = pos - hy * 12;
                    const int gh = h0 - 2 + hy, gw = w0 - 2 + hx;
                    const bool ok = (gh >= 0) & (gh < 64) & (gw >= 0) & (gw < 64);
                    v = ok ? ref_value[(size_t)((((b << 6) + gh) << 6) + gw) * 128 + ch] : 0.f;
                } else {
                    const int t2 = pos - 96;
                    v = main_value[(size_t)((((b << 6) + h0 + (t2 >> 3)) << 6) + (w0 + (t2 & 7))) * 128 + ch];
                }
                hv[j] = (_Float16)v;
            }
            *(v8h*)(S + B_OFF + swz(ch, pb)) = hv;
        }
        // softmax: 4 pixels per wave; OOB cols read logit 0 (zero rows) = zero-pad semantics
        #pragma unroll
        for (int i = 0; i < 4; ++i) {
            const int t = (w << 2) + i;
            const int ty = t >> 3, tx = t & 7;
            const bool act = lane < 26;
            int col;
            if (lane < 25) {
                const int dy = lane / 5 - 2, dx = lane % 5 - 2;
                col = (ty + dy + 2) * 12 + (tx + dx + 2);
            } else col = 96 + t;                      // self column
            const float lg = act ? *(const float*)(S + L_OFF + (t << 9) + (col << 2)) : -INFINITY;
            float m = lg;
            #pragma unroll
            for (int off = 32; off; off >>= 1) m = fmaxf(m, __shfl_xor(m, off));
            const float e = act ? __expf(lg - m) : 0.f;
            float s = e;
            #pragma unroll
            for (int off = 32; off; off >>= 1) s += __shfl_xor(s, off);
            if (act)
                *(_Float16*)(S + P_OFF + swz(t, col >> 3) + ((col & 7) << 1)) = (_Float16)(e / s);
        }
    }
    __syncthreads();

    // ================= epoch 4: O = P * V via MFMA, store ==================
    {
        const int prow = (mt << 4) + l15;
        const int v0r  = (ntp << 4) + l15, v1r = v0r + 16;   // VT rows = out channels
        v4f acc0 = {0,0,0,0}, acc1 = {0,0,0,0};
        #pragma unroll
        for (int ks = 0; ks < 4; ++ks) {
            const int c16 = (ks << 2) + quad;
            const v8h pa  = *(const v8h*)(S + P_OFF + swz(prow, c16));
            const v8h vt0 = *(const v8h*)(S + B_OFF + swz(v0r,  c16));
            const v8h vt1 = *(const v8h*)(S + B_OFF + swz(v1r,  c16));
            acc0 = __builtin_amdgcn_mfma_f32_16x16x32_f16(pa, vt0, acc0, 0, 0, 0);
            acc1 = __builtin_amdgcn_mfma_f32_16x16x32_f16(pa, vt1, acc1, 0, 0, 0);
        }
        #pragma unroll
        for (int j = 0; j < 4; ++j) {
            const int px = (mt << 4) + (quad << 2) + j;
            const size_t gbase =
                (size_t)((((b << 6) + h0 + (px >> 3)) << 6) + (w0 + (px & 7))) * 128;
            out[gbase + ((ntp    ) << 4) + l15] = acc0[j];
            out[gbase + ((ntp + 1) << 4) + l15] = acc1[j];
        }
    }
}

extern "C" void kernel_launch(void* const* d_in, const int* in_sizes, int n_in,
                              void* d_out, int out_size, void* d_ws, size_t ws_size,
                              hipStream_t stream) {
    const float* main_      = (const float*)d_in[0];
    const float* main_value = (const float*)d_in[1];
    const float* ref        = (const float*)d_in[2];
    const float* ref_value  = (const float*)d_in[3];
    float* out = (float*)d_out;

    dim3 grid(4 * 16 * 8), block(512);   // 512 blocks (4x8 pixel tiles), 2 blocks/CU
    local_attn_mfma<<<grid, block, 0, stream>>>(main_, main_value, ref, ref_value, out);
}

// Round 5
// 98.642 us; speedup vs baseline: 1.3868x; 1.0043x over previous
//
#include <hip/hip_runtime.h>
#include <math.h>

typedef _Float16 v8h __attribute__((ext_vector_type(8)));
typedef float    v4f __attribute__((ext_vector_type(4)));

// LDS layout (65536 B):
//  B16 [0, 32768): 128 rows x 128 fp16 (256 B rows, XOR-swizzled 16B chunks)
//      rows 0..95  = ref halo (8x12, zero rows for OOB -> exact zero-pad semantics)
//      rows 96..127 = main pixel rows (fp16 hi) == A_hi
//      REUSED in epoch 3/4 as VT: rows = value-channel, cols = position 0..127
//  ALO [32768, 40960): 32 x 128 fp16 = lo part of main (fp16 hi/lo split)
//  L   [40960, 57344): 32 x 128 fp32 logits
//  P   [57344, 65536): 32 x 128 fp16 attn matrix (zero except 26 cols/row)
#define B_OFF   0
#define ALO_OFF 32768
#define L_OFF   40960
#define P_OFF   57344

// byte offset of 16B chunk c16 in row r (256 B rows, XOR bank swizzle)
__device__ __forceinline__ int swz(int r, int c16) {
    return (r << 8) + ((c16 ^ (r & 15)) << 4);
}

__global__ __launch_bounds__(512, 4) void local_attn_mfma2(
    const float* __restrict__ main_,
    const float* __restrict__ main_value,
    const float* __restrict__ ref,
    const float* __restrict__ ref_value,
    float* __restrict__ out)
{
    __shared__ __align__(16) char S[65536];

    const int tid = threadIdx.x;
    const int bid = blockIdx.x;
    const int b  = bid >> 7;
    const int h0 = ((bid >> 3) & 15) << 2;   // 4-row tiles
    const int w0 = (bid & 7) << 3;           // 8-col tiles
    const int lane = tid & 63, w = tid >> 6;

    // ========== epoch 1a: issue A/B staging loads (oldest in vmcnt queue) ==========
    const int r = tid >> 2;          // 0..127: B row
    const int q = tid & 3;           // channel quarter (32 ch)
    bool valid = true;
    const float* src;
    if (r < 96) {
        const int hy = r / 12, hx = r - hy * 12;
        const int gh = h0 - 2 + hy, gw = w0 - 2 + hx;
        valid = (gh >= 0) & (gh < 64) & (gw >= 0) & (gw < 64);
        src = ref + (size_t)((((b << 6) + (valid ? gh : 0)) << 6) + (valid ? gw : 0)) * 128;
    } else {
        const int t = r - 96;
        src = main_ + (size_t)((((b << 6) + h0 + (t >> 3)) << 6) + (w0 + (t & 7))) * 128;
    }
    float4 e1[8];
    #pragma unroll
    for (int g = 0; g < 8; ++g)
        e1[g] = valid ? *(const float4*)(src + (q << 5) + (g << 2)) : make_float4(0, 0, 0, 0);

    // ========== prefetch V (epoch-3 data) — overlaps epochs 1-2 ==========
    float pv[4][8];
    #pragma unroll
    for (int i = 0; i < 4; ++i) {
        const int tk = w + (i << 3);              // 0..31 tasks
        const int pb = tk & 15;                   // position block (8 pos)
        const int ch = ((tk >> 4) << 6) + lane;   // value channel 0..127
        #pragma unroll
        for (int j = 0; j < 8; ++j) {
            const int pos = (pb << 3) + j;        // wave-uniform
            float v = 0.f;
            if (pos < 96) {
                const int hy = pos / 12, hx = pos - hy * 12;
                const int gh = h0 - 2 + hy, gw = w0 - 2 + hx;
                if ((gh >= 0) & (gh < 64) & (gw >= 0) & (gw < 64))
                    v = ref_value[(size_t)((((b << 6) + gh) << 6) + gw) * 128 + ch];
            } else {
                const int t2 = pos - 96;
                v = main_value[(size_t)((((b << 6) + h0 + (t2 >> 3)) << 6) + (w0 + (t2 & 7))) * 128 + ch];
            }
            pv[i][j] = v;
        }
    }

    // ========== epoch 1b: convert + write A/B to LDS, zero P ==========
    #pragma unroll
    for (int g = 0; g < 4; ++g) {
        const float4 v0 = e1[2 * g], v1 = e1[2 * g + 1];
        float a8[8] = {v0.x, v0.y, v0.z, v0.w, v1.x, v1.y, v1.z, v1.w};
        v8h hi;
        #pragma unroll
        for (int j = 0; j < 8; ++j) hi[j] = (_Float16)a8[j];
        *(v8h*)(S + B_OFF + swz(r, (q << 2) + g)) = hi;
        if (r >= 96) {                 // lo part of main (fp16 hi/lo split)
            v8h lo;
            #pragma unroll
            for (int j = 0; j < 8; ++j) lo[j] = (_Float16)(a8[j] - (float)hi[j]);
            *(v8h*)(S + ALO_OFF + swz(r - 96, (q << 2) + g)) = lo;
        }
    }
    *(uint4*)(S + P_OFF + tid * 16) = make_uint4(0, 0, 0, 0);

    // convert prefetched V to fp16 (frees 32 regs -> 16 held through epoch 2)
    v8h hv[4];
    #pragma unroll
    for (int i = 0; i < 4; ++i)
        #pragma unroll
        for (int j = 0; j < 8; ++j) hv[i][j] = (_Float16)pv[i][j];

    __syncthreads();

    const int l15 = lane & 15, quad = lane >> 4;
    const int mt  = w >> 2;              // m-tile (16 pixels)
    const int ntp = (w & 3) << 1;        // first of 2 n-tiles

    // ========== epoch 2: L = (A_hi + A_lo) * B^T via MFMA ==========
    {
        const int arow = 96 + (mt << 4) + l15;
        const int lrow = (mt << 4) + l15;
        const int b0r  = (ntp << 4) + l15, b1r = b0r + 16;
        v4f acc0 = {0, 0, 0, 0}, acc1 = {0, 0, 0, 0};
        #pragma unroll
        for (int ks = 0; ks < 4; ++ks) {
            const int c16 = (ks << 2) + quad;
            const v8h ahi = *(const v8h*)(S + B_OFF   + swz(arow, c16));
            const v8h alo = *(const v8h*)(S + ALO_OFF + swz(lrow, c16));
            const v8h bb0 = *(const v8h*)(S + B_OFF   + swz(b0r,  c16));
            const v8h bb1 = *(const v8h*)(S + B_OFF   + swz(b1r,  c16));
            acc0 = __builtin_amdgcn_mfma_f32_16x16x32_f16(ahi, bb0, acc0, 0, 0, 0);
            acc0 = __builtin_amdgcn_mfma_f32_16x16x32_f16(alo, bb0, acc0, 0, 0, 0);
            acc1 = __builtin_amdgcn_mfma_f32_16x16x32_f16(ahi, bb1, acc1, 0, 0, 0);
            acc1 = __builtin_amdgcn_mfma_f32_16x16x32_f16(alo, bb1, acc1, 0, 0, 0);
        }
        // C layout: col = lane&15 (n), row = quad*4 + reg (m)
        #pragma unroll
        for (int j = 0; j < 4; ++j) {
            const int px = (mt << 4) + (quad << 2) + j;
            *(float*)(S + L_OFF + (px << 9) + ((((ntp    ) << 4) + l15) << 2)) = acc0[j];
            *(float*)(S + L_OFF + (px << 9) + ((((ntp + 1) << 4) + l15) << 2)) = acc1[j];
        }
    }
    __syncthreads();

    // ========== epoch 3: VT writes (overwrite B16) + softmax -> P ==========
    {
        #pragma unroll
        for (int i = 0; i < 4; ++i) {
            const int tk = w + (i << 3);
            const int pb = tk & 15;
            const int ch = ((tk >> 4) << 6) + lane;
            *(v8h*)(S + B_OFF + swz(ch, pb)) = hv[i];
        }
        // softmax: 2 pixels per wave-half (butterfly stays within 32 lanes)
        const int half = lane >> 5;
        const int l    = lane & 31;
        #pragma unroll
        for (int i = 0; i < 2; ++i) {
            const int t = (w << 2) + (i << 1) + half;
            const int ty = t >> 3, tx = t & 7;
            const bool act = l < 26;
            int col;
            if (l < 25) {
                const int dy = l / 5 - 2, dx = l % 5 - 2;
                col = (ty + dy + 2) * 12 + (tx + dx + 2);
            } else col = 96 + t;                  // self column
            const float lg = act ? *(const float*)(S + L_OFF + (t << 9) + (col << 2)) : -INFINITY;
            float m = lg;
            #pragma unroll
            for (int off = 16; off; off >>= 1) m = fmaxf(m, __shfl_xor(m, off));
            const float e = act ? __expf(lg - m) : 0.f;
            float s = e;
            #pragma unroll
            for (int off = 16; off; off >>= 1) s += __shfl_xor(s, off);
            if (act)
                *(_Float16*)(S + P_OFF + swz(t, col >> 3) + ((col & 7) << 1)) = (_Float16)(e / s);
        }
    }
    __syncthreads();

    // ========== epoch 4: O = P * V via MFMA, store ==========
    {
        const int prow = (mt << 4) + l15;
        const int v0r  = (ntp << 4) + l15, v1r = v0r + 16;   // VT rows = out channels
        v4f acc0 = {0, 0, 0, 0}, acc1 = {0, 0, 0, 0};
        #pragma unroll
        for (int ks = 0; ks < 4; ++ks) {
            const int c16 = (ks << 2) + quad;
            const v8h pa  = *(const v8h*)(S + P_OFF + swz(prow, c16));
            const v8h vt0 = *(const v8h*)(S + B_OFF + swz(v0r,  c16));
            const v8h vt1 = *(const v8h*)(S + B_OFF + swz(v1r,  c16));
            acc0 = __builtin_amdgcn_mfma_f32_16x16x32_f16(pa, vt0, acc0, 0, 0, 0);
            acc1 = __builtin_amdgcn_mfma_f32_16x16x32_f16(pa, vt1, acc1, 0, 0, 0);
        }
        #pragma unroll
        for (int j = 0; j < 4; ++j) {
            const int px = (mt << 4) + (quad << 2) + j;
            const size_t gbase =
                (size_t)((((b << 6) + h0 + (px >> 3)) << 6) + (w0 + (px & 7))) * 128;
            out[gbase + ((ntp    ) << 4) + l15] = acc0[j];
            out[gbase + ((ntp + 1) << 4) + l15] = acc1[j];
        }
    }
}

extern "C" void kernel_launch(void* const* d_in, const int* in_sizes, int n_in,
                              void* d_out, int out_size, void* d_ws, size_t ws_size,
                              hipStream_t stream) {
    const float* main_      = (const float*)d_in[0];
    const float* main_value = (const float*)d_in[1];
    const float* ref        = (const float*)d_in[2];
    const float* ref_value  = (const float*)d_in[3];
    float* out = (float*)d_out;

    dim3 grid(4 * 16 * 8), block(512);   // 512 blocks (4x8 pixel tiles), 2 blocks/CU
    local_attn_mfma2<<<grid, block, 0, stream>>>(main_, main_value, ref, ref_value, out);
}